// Round 5
// baseline (275.217 us; speedup 1.0000x reference)
//
#include <hip/hip_runtime.h>
#include <math.h>

typedef __attribute__((ext_vector_type(8))) short short8;
typedef __attribute__((ext_vector_type(4))) float f32x4;
typedef __attribute__((ext_vector_type(16))) float f32x16;

#define NTAP 125
#define DCH 32

static __device__ __forceinline__ unsigned short f2bf(float f) {
    union { float f; unsigned u; } v; v.f = f;
    unsigned u = v.u;
    return (unsigned short)((u + 0x7FFFu + ((u >> 16) & 1u)) >> 16);
}

static __device__ __forceinline__ void gld_lds16(const void* g, void* l) {
    __builtin_amdgcn_global_load_lds(
        (const __attribute__((address_space(1))) unsigned int*)g,
        (__attribute__((address_space(3))) unsigned int*)l, 16, 0, 0);
}

// ---------------------------------------------------------------------------
// Kernel 1: build conv weights kw[ci=32][tap=125][co=32] (fp32).
// Skip connection folded into center tap 62. (verified R0-R3)
// ---------------------------------------------------------------------------
__global__ __launch_bounds__(128) void build_kern(
    const float* __restrict__ weight,
    const float* __restrict__ w_sc0,
    const float* __restrict__ w_sc1,
    float* __restrict__ kw)
{
    const int t = blockIdx.x;
    const int dx = t / 25, dy = (t / 5) % 5, dz = t % 5;
    const float px = dx - 2.0f, py = dy - 2.0f, pz = dz - 2.0f;
    const float d = sqrtf(px * px + py * py + pz * pz);

    const float stepv = 2.5f / 6.0f;
    const float embc = 1.14136f * expf(2.0f);
    float emb[5];
#pragma unroll
    for (int n = 0; n < 5; ++n) {
        float diff = (d - stepv * (float)(n + 1)) / stepv;
        float a = diff + 1.0f, bb = 1.0f - diff;
        float v = 0.0f;
        if (a > 0.0f && bb > 0.0f)
            v = embc * expf(-1.0f / a) * expf(-1.0f / bb);
        emb[n] = v;
    }

    const float inv_d = (d > 0.0f) ? 1.0f / d : 0.0f;
    const float ux = px * inv_d, uy = py * inv_d, uz = pz * inv_d;
    const float s3 = 1.73205081f, s5 = 2.23606798f, s15 = 3.87298335f;
    float sh[9];
    sh[0] = 1.0f;
    sh[1] = s3 * ux; sh[2] = s3 * uy; sh[3] = s3 * uz;
    sh[4] = s15 * ux * uz;
    sh[5] = s15 * ux * uy;
    sh[6] = s5 * (uy * uy - 0.5f * (ux * ux + uz * uz));
    sh[7] = s15 * uy * uz;
    sh[8] = 0.5f * s15 * (uz * uz - ux * ux);

    const float i_s2 = 0.70710678f, i_s6 = 0.40824829f, i_s5 = 0.44721360f;
    float T[3][3];
    T[0][0] = i_s5 * (-sh[6] * i_s6 - sh[8] * i_s2);
    T[0][1] = i_s5 * (sh[5] * i_s2);
    T[0][2] = i_s5 * (sh[4] * i_s2);
    T[1][0] = T[0][1];
    T[1][1] = i_s5 * (2.0f * sh[6] * i_s6);
    T[1][2] = i_s5 * (sh[7] * i_s2);
    T[2][0] = T[0][2];
    T[2][1] = T[1][2];
    T[2][2] = i_s5 * (-sh[6] * i_s6 + sh[8] * i_s2);

    __shared__ float Wt[320];
    for (int col = threadIdx.x; col < 320; col += 128) {
        float a = 0.0f;
#pragma unroll
        for (int n = 0; n < 5; ++n) a += emb[n] * weight[n * 320 + col];
        Wt[col] = a * (1.0f / 125.0f);
    }
    __syncthreads();

    const float pw0 = 0.25f;
    const float pw1 = 0.35355339f;
    const float inv_s3 = 0.57735027f;
    const float inv_s8 = 0.35355339f;

    for (int idx = threadIdx.x; idx < 1024; idx += 128) {
        const int o = idx >> 5, i = idx & 31;
        float val;
        if (o < 8) {
            if (i < 8) {
                val = pw0 * Wt[i * 8 + o];
            } else {
                const int u = (i - 8) / 3, m = (i - 8) % 3;
                val = pw0 * inv_s3 * Wt[192 + u * 8 + o] * sh[1 + m];
            }
        } else {
            const int v = (o - 8) / 3, k = (o - 8) % 3;
            if (i < 8) {
                val = pw1 * inv_s3 * Wt[64 + i * 8 + v] * sh[1 + k];
            } else {
                const int u = (i - 8) / 3, m = (i - 8) % 3;
                float tv = Wt[256 + u * 8 + v] * T[m][k];
                if (m == k) tv += inv_s3 * Wt[128 + u * 8 + v];
                val = pw1 * tv;
            }
        }
        if (t == 62) {
            if (o < 8 && i < 8) {
                val += inv_s8 * w_sc0[i * 8 + o];
            } else if (o >= 8 && i >= 8) {
                const int u = (i - 8) / 3, m = (i - 8) % 3;
                const int v = (o - 8) / 3, k = (o - 8) % 3;
                if (m == k) val += inv_s8 * w_sc1[u * 8 + v];
            }
        }
        kw[(i * NTAP + t) * DCH + o] = val;
    }
}

// ---------------------------------------------------------------------------
// Kernel 2: pack kw -> bf16 B-fragments for mfma_f32_32x32x16_bf16.
// kwb[tap][kh][lane][8]: lane l holds B[k=(l>>5)*8+j][n=l&31],
// ci = kh*16 + (l>>5)*8 + j, co = l&31.
// ---------------------------------------------------------------------------
__global__ __launch_bounds__(128) void pack_b(
    const float* __restrict__ kw, unsigned short* __restrict__ kwb)
{
    const int t = blockIdx.x;
    const int tid = threadIdx.x;
    const int kh = tid >> 6, l = tid & 63;
    const int co = l & 31;
    const int cib = kh * 16 + (l >> 5) * 8;
    unsigned short v[8];
#pragma unroll
    for (int j = 0; j < 8; ++j)
        v[j] = f2bf(kw[((cib + j) * NTAP + t) * DCH + co]);
    uint4 o;
    o.x = (unsigned)v[0] | ((unsigned)v[1] << 16);
    o.y = (unsigned)v[2] | ((unsigned)v[3] << 16);
    o.z = (unsigned)v[4] | ((unsigned)v[5] << 16);
    o.w = (unsigned)v[6] | ((unsigned)v[7] << 16);
    *reinterpret_cast<uint4*>(kwb + ((size_t)(t * 2 + kh) * 64 + l) * 8) = o;
}

// ---------------------------------------------------------------------------
// Kernel 3: transpose x fp32 [b][ci][X][Y][Z] -> bf16 xt[b][64][64][68][32]
// with z-halo of 2 on each side (z_idx = z + 2), halo zero-filled here so
// conv A-loads need no per-lane z masking. Full xt coverage every launch
// (interior + halo) -> safe under workspace poisoning.
// ---------------------------------------------------------------------------
__global__ __launch_bounds__(256) void xpose(
    const float* __restrict__ x, unsigned short* __restrict__ xt)
{
    const int xx = blockIdx.x, yy = blockIdx.y, b = blockIdx.z;
    const int t = threadIdx.x;
    const int z = t & 63, part = t >> 6;
    const float* src = x + ((((size_t)b * 32) * 64 + xx) * 64 + yy) * 64 + z;
    unsigned short v[8];
#pragma unroll
    for (int j = 0; j < 8; ++j)
        v[j] = f2bf(src[(size_t)(part * 8 + j) * 262144]);
    uint4 o;
    o.x = (unsigned)v[0] | ((unsigned)v[1] << 16);
    o.y = (unsigned)v[2] | ((unsigned)v[3] << 16);
    o.z = (unsigned)v[4] | ((unsigned)v[5] << 16);
    o.w = (unsigned)v[6] | ((unsigned)v[7] << 16);
    unsigned short* row =
        xt + (((size_t)b * 64 + xx) * 64 + yy) * 2176;   // 68*32 shorts/row
    *reinterpret_cast<uint4*>(row + (size_t)(z + 2) * 32 + part * 8) = o;
    if (t < 16) {
        const int zi = t >> 2;                    // 0..3
        const int z_idx = (zi < 2) ? zi : 64 + zi; // 0,1,66,67
        uint4 zz; zz.x = zz.y = zz.z = zz.w = 0u;
        *reinterpret_cast<uint4*>(row + (size_t)z_idx * 32 + (t & 3) * 8) = zz;
    }
}

__global__ void zero_fill(float4* p) {
    float4 z = make_float4(0.f, 0.f, 0.f, 0.f);
#pragma unroll
    for (int i = 0; i < 4; ++i) p[threadIdx.x + 256 * i] = z;
}

// ---------------------------------------------------------------------------
// Kernel 4: implicit-GEMM conv via mfma_f32_32x32x16_bf16.
// R5: NO A-slab in LDS at all. LDS holds only Bs (static __shared__,
// 51200 B), restaged once per dy between two barriers. A fragments are
// loaded directly from the z-halo-padded xt with global_load_dwordx4:
// per step each x-slice is read exactly once, dz/kh reuse (5x) is captured
// by L1 (per-CU step footprint ~35 KB). x/y OOB -> zero-page base select
// (branchless, wave-uniform). This removes, by construction, the
// compiler-inserted vmcnt(0)-before-ds_read serialization that capped
// R1-R4 at ~44-46% MfmaUtil (plain VMEM loads don't interact with the
// DS-wait domain; no LDS-DMA is outstanding during compute). No barriers
// inside a dy (10 syncthreads/block total, was 80).
// Block 512 thr (8 waves), tile 4x*8y*64z, grid 16*8*2 = 256 = 1 block/CU.
// Wave wv: zh = wv&1, oy pair = (wv>>1)*2 + {0,1}; 8 acc (4ox x 2oy).
// ---------------------------------------------------------------------------
__global__ __launch_bounds__(512, 2) void conv_mfma(
    const unsigned short* __restrict__ xt,   // [b][64][64][68][32] bf16
    const unsigned short* __restrict__ kwb,  // [125][2][64][8]
    const unsigned short* __restrict__ zpg,  // 16 KB zeros
    float* __restrict__ out)                 // [b][32][64][64][64]
{
    __shared__ unsigned short Bs[25600];     // 51200 B: [25 tap][2 kh][64][16B]

    const int tid = threadIdx.x;
    const int lane = tid & 63;
    const int wv = tid >> 6;                 // 0..7
    const int oyp = wv >> 1, zh = wv & 1;    // oy pair 0..3, z half
    const int x0 = blockIdx.x * 4, y0 = blockIdx.y * 8;
    const int b = blockIdx.z;
    const int l31 = lane & 31, hi = lane >> 5;

    // per-lane A base offset within a (slice,row): z_idx0*32 + hi*8 shorts
    const int lanebase = (zh * 32 + l31) * 32 + hi * 8;
    const char* bsp = (const char*)Bs;
    const int bbase = lane * 16;

    // Bs staging precompute: 3200 chunks, c = tid + k*512
    int bsrc[7];
#pragma unroll
    for (int k = 0; k < 7; ++k) {
        const int c = tid + k * 512;
        const int tp = c >> 7, rem = c & 127;
        const int dxx = tp / 5, dzz = tp - dxx * 5;
        bsrc[k] = (dxx * 25 + dzz) * 128 + rem;
    }

    f32x16 acc[2][4];
#pragma unroll
    for (int oyi = 0; oyi < 2; ++oyi)
#pragma unroll
        for (int ox = 0; ox < 4; ++ox)
#pragma unroll
            for (int e = 0; e < 16; ++e) acc[oyi][ox][e] = 0.0f;

    for (int dy = 0; dy < 5; ++dy) {
        // restage Bs(dy): previous readers done / staged data visible
        __syncthreads();
#pragma unroll
        for (int k = 0; k < 7; ++k) {
            const int c0 = wv * 64 + k * 512;   // wave-uniform dest base
            if (c0 < 3200) {
                gld_lds16(kwb + ((size_t)(bsrc[k] + dy * 640)) * 8,
                          (char*)Bs + c0 * 16);
            }
        }
        __syncthreads();

        const int yy0 = y0 + oyp * 2 + dy - 2;       // wave-uniform
        const bool y0ok = ((unsigned)yy0 < 64u);
        const bool y1ok = ((unsigned)(yy0 + 1) < 64u);

#pragma unroll
        for (int xl = 0; xl < 8; ++xl) {
            const int xx = x0 + xl - 2;
            const bool xok = ((unsigned)xx < 64u);

            // A base pointers (branchless zero-page select, wave-uniform ok)
            const long long sb =
                ((long long)(b * 64) + xx) * 139264 + lanebase;
            const unsigned short* p0 = (xok && y0ok)
                ? xt + sb + (long long)yy0 * 2176 : zpg + lanebase;
            const unsigned short* p1 = (xok && y1ok)
                ? xt + sb + (long long)(yy0 + 1) * 2176 : zpg + lanebase;

            // A fragments direct from global (L1 captures dz/kh reuse)
            short8 A0[5][2], A1[5][2];
#pragma unroll
            for (int dz = 0; dz < 5; ++dz)
#pragma unroll
                for (int kh = 0; kh < 2; ++kh) {
                    A0[dz][kh] = *reinterpret_cast<const short8*>(
                        reinterpret_cast<const char*>(p0) + dz * 64 + kh * 32);
                    A1[dz][kh] = *reinterpret_cast<const short8*>(
                        reinterpret_cast<const char*>(p1) + dz * 64 + kh * 32);
                }

            // compute: B fragment shared across both oy accumulators
#pragma unroll
            for (int dz = 0; dz < 5; ++dz)
#pragma unroll
                for (int kh = 0; kh < 2; ++kh) {
                    const short8 a0 = A0[dz][kh];
                    const short8 a1 = A1[dz][kh];
#pragma unroll
                    for (int ox = 0; ox < 4; ++ox) {
                        const int dxv = xl - ox;
                        if (dxv < 0 || dxv > 4) continue;
                        const short8 bf = *reinterpret_cast<const short8*>(
                            bsp + bbase + (((dxv * 5 + dz) * 2 + kh) << 10));
                        acc[0][ox] = __builtin_amdgcn_mfma_f32_32x32x16_bf16(
                            a0, bf, acc[0][ox], 0, 0, 0);
                        acc[1][ox] = __builtin_amdgcn_mfma_f32_32x32x16_bf16(
                            a1, bf, acc[1][ox], 0, 0, 0);
                    }
                }
        }
    }

    // epilogue: D lane l: co = l&31, z = zh*32 + rq*8 + (l>>5)*4 + (r&3)
#pragma unroll
    for (int oyi = 0; oyi < 2; ++oyi) {
        const int yy = y0 + oyp * 2 + oyi;
#pragma unroll
        for (int ox = 0; ox < 4; ++ox) {
            float* base = out +
                ((((size_t)b * 32 + l31) * 64 + (x0 + ox)) * 64 + yy) * 64 +
                zh * 32 + hi * 4;
#pragma unroll
            for (int rq = 0; rq < 4; ++rq) {
                f32x4 v = { acc[oyi][ox][rq * 4 + 0], acc[oyi][ox][rq * 4 + 1],
                            acc[oyi][ox][rq * 4 + 2], acc[oyi][ox][rq * 4 + 3] };
                *reinterpret_cast<f32x4*>(base + rq * 8) = v;
            }
        }
    }
}

// ---------------------------------------------------------------------------
extern "C" void kernel_launch(void* const* d_in, const int* in_sizes, int n_in,
                              void* d_out, int out_size, void* d_ws, size_t ws_size,
                              hipStream_t stream) {
    const float* x      = (const float*)d_in[0];
    const float* weight = (const float*)d_in[1];
    const float* w_sc0  = (const float*)d_in[2];
    const float* w_sc1  = (const float*)d_in[3];
    float* out = (float*)d_out;

    char* ws = (char*)d_ws;
    unsigned short* xt  = (unsigned short*)ws;                 // 35,651,584 B
    float*          kwp = (float*)(ws + 35651584);             //    512,000 B
    unsigned short* kwb = (unsigned short*)(ws + 36163584);    //    256,000 B
    unsigned short* zpg = (unsigned short*)(ws + 36419584);    //     16,384 B

    hipLaunchKernelGGL(build_kern, dim3(NTAP), dim3(128), 0, stream,
                       weight, w_sc0, w_sc1, kwp);
    hipLaunchKernelGGL(pack_b, dim3(NTAP), dim3(128), 0, stream, kwp, kwb);
    hipLaunchKernelGGL(xpose, dim3(64, 64, 2), dim3(256), 0, stream, x, xt);
    hipLaunchKernelGGL(zero_fill, dim3(1), dim3(256), 0, stream, (float4*)zpg);
    hipLaunchKernelGGL(conv_mfma, dim3(16, 8, 2), dim3(512), 0, stream,
                       xt, kwb, zpg, out);
}

// Round 6
// 148.789 us; speedup vs baseline: 1.8497x; 1.8497x over previous
//
#include <hip/hip_runtime.h>
#include <math.h>

typedef __attribute__((ext_vector_type(8))) short short8;
typedef __attribute__((ext_vector_type(4))) float f32x4;
typedef __attribute__((ext_vector_type(16))) float f32x16;

#define NTAP 125
#define DCH 32

static __device__ __forceinline__ unsigned short f2bf(float f) {
    union { float f; unsigned u; } v; v.f = f;
    unsigned u = v.u;
    return (unsigned short)((u + 0x7FFFu + ((u >> 16) & 1u)) >> 16);
}

static __device__ __forceinline__ void gld_lds16(const void* g, void* l) {
    __builtin_amdgcn_global_load_lds(
        (const __attribute__((address_space(1))) unsigned int*)g,
        (__attribute__((address_space(3))) unsigned int*)l, 16, 0, 0);
}

// ---------------------------------------------------------------------------
// Kernel 1 (fused build+pack): build conv weights for tap t in LDS, then
// pack to bf16 B-fragments kwb[tap][kh][lane][8] for mfma_f32_32x32x16_bf16.
// Skip connection folded into center tap 62. (math verified R0-R5)
// ---------------------------------------------------------------------------
__global__ __launch_bounds__(128) void build_pack(
    const float* __restrict__ weight,
    const float* __restrict__ w_sc0,
    const float* __restrict__ w_sc1,
    unsigned short* __restrict__ kwb)
{
    const int t = blockIdx.x;
    const int dx = t / 25, dy = (t / 5) % 5, dz = t % 5;
    const float px = dx - 2.0f, py = dy - 2.0f, pz = dz - 2.0f;
    const float d = sqrtf(px * px + py * py + pz * pz);

    const float stepv = 2.5f / 6.0f;
    const float embc = 1.14136f * expf(2.0f);
    float emb[5];
#pragma unroll
    for (int n = 0; n < 5; ++n) {
        float diff = (d - stepv * (float)(n + 1)) / stepv;
        float a = diff + 1.0f, bb = 1.0f - diff;
        float v = 0.0f;
        if (a > 0.0f && bb > 0.0f)
            v = embc * expf(-1.0f / a) * expf(-1.0f / bb);
        emb[n] = v;
    }

    const float inv_d = (d > 0.0f) ? 1.0f / d : 0.0f;
    const float ux = px * inv_d, uy = py * inv_d, uz = pz * inv_d;
    const float s3 = 1.73205081f, s5 = 2.23606798f, s15 = 3.87298335f;
    float sh[9];
    sh[0] = 1.0f;
    sh[1] = s3 * ux; sh[2] = s3 * uy; sh[3] = s3 * uz;
    sh[4] = s15 * ux * uz;
    sh[5] = s15 * ux * uy;
    sh[6] = s5 * (uy * uy - 0.5f * (ux * ux + uz * uz));
    sh[7] = s15 * uy * uz;
    sh[8] = 0.5f * s15 * (uz * uz - ux * ux);

    const float i_s2 = 0.70710678f, i_s6 = 0.40824829f, i_s5 = 0.44721360f;
    float T[3][3];
    T[0][0] = i_s5 * (-sh[6] * i_s6 - sh[8] * i_s2);
    T[0][1] = i_s5 * (sh[5] * i_s2);
    T[0][2] = i_s5 * (sh[4] * i_s2);
    T[1][0] = T[0][1];
    T[1][1] = i_s5 * (2.0f * sh[6] * i_s6);
    T[1][2] = i_s5 * (sh[7] * i_s2);
    T[2][0] = T[0][2];
    T[2][1] = T[1][2];
    T[2][2] = i_s5 * (-sh[6] * i_s6 + sh[8] * i_s2);

    __shared__ float Wt[320];
    __shared__ float kws[1024];              // [ci=32][co=32] for this tap
    for (int col = threadIdx.x; col < 320; col += 128) {
        float a = 0.0f;
#pragma unroll
        for (int n = 0; n < 5; ++n) a += emb[n] * weight[n * 320 + col];
        Wt[col] = a * (1.0f / 125.0f);
    }
    __syncthreads();

    const float pw0 = 0.25f;
    const float pw1 = 0.35355339f;
    const float inv_s3 = 0.57735027f;
    const float inv_s8 = 0.35355339f;

    for (int idx = threadIdx.x; idx < 1024; idx += 128) {
        const int o = idx >> 5, i = idx & 31;
        float val;
        if (o < 8) {
            if (i < 8) {
                val = pw0 * Wt[i * 8 + o];
            } else {
                const int u = (i - 8) / 3, m = (i - 8) % 3;
                val = pw0 * inv_s3 * Wt[192 + u * 8 + o] * sh[1 + m];
            }
        } else {
            const int v = (o - 8) / 3, k = (o - 8) % 3;
            if (i < 8) {
                val = pw1 * inv_s3 * Wt[64 + i * 8 + v] * sh[1 + k];
            } else {
                const int u = (i - 8) / 3, m = (i - 8) % 3;
                float tv = Wt[256 + u * 8 + v] * T[m][k];
                if (m == k) tv += inv_s3 * Wt[128 + u * 8 + v];
                val = pw1 * tv;
            }
        }
        if (t == 62) {
            if (o < 8 && i < 8) {
                val += inv_s8 * w_sc0[i * 8 + o];
            } else if (o >= 8 && i >= 8) {
                const int u = (i - 8) / 3, m = (i - 8) % 3;
                const int v = (o - 8) / 3, k = (o - 8) % 3;
                if (m == k) val += inv_s8 * w_sc1[u * 8 + v];
            }
        }
        kws[i * 32 + o] = val;
    }
    __syncthreads();

    // pack: kwb[tap][kh][lane][8], ci = kh*16 + (l>>5)*8 + j, co = l&31
    const int tid = threadIdx.x;
    const int kh = tid >> 6, l = tid & 63;
    const int co = l & 31;
    const int cib = kh * 16 + (l >> 5) * 8;
    unsigned short v[8];
#pragma unroll
    for (int j = 0; j < 8; ++j)
        v[j] = f2bf(kws[(cib + j) * 32 + co]);
    uint4 o;
    o.x = (unsigned)v[0] | ((unsigned)v[1] << 16);
    o.y = (unsigned)v[2] | ((unsigned)v[3] << 16);
    o.z = (unsigned)v[4] | ((unsigned)v[5] << 16);
    o.w = (unsigned)v[6] | ((unsigned)v[7] << 16);
    *reinterpret_cast<uint4*>(kwb + ((size_t)(t * 2 + kh) * 64 + l) * 8) = o;
}

// ---------------------------------------------------------------------------
// Kernel 2: transpose x fp32 [b][ci][X][Y][Z] -> bf16 x_t[b][X][Y][Z][ci=32]
// ---------------------------------------------------------------------------
__global__ __launch_bounds__(256) void xpose(
    const float* __restrict__ x, unsigned short* __restrict__ xt)
{
    const int xx = blockIdx.x, yy = blockIdx.y, b = blockIdx.z;
    const int t = threadIdx.x;
    const int z = t & 63, part = t >> 6;
    const float* src = x + ((((size_t)b * 32) * 64 + xx) * 64 + yy) * 64 + z;
    unsigned short v[8];
#pragma unroll
    for (int j = 0; j < 8; ++j)
        v[j] = f2bf(src[(size_t)(part * 8 + j) * 262144]);
    uint4 o;
    o.x = (unsigned)v[0] | ((unsigned)v[1] << 16);
    o.y = (unsigned)v[2] | ((unsigned)v[3] << 16);
    o.z = (unsigned)v[4] | ((unsigned)v[5] << 16);
    o.w = (unsigned)v[6] | ((unsigned)v[7] << 16);
    *reinterpret_cast<uint4*>(
        xt + ((((size_t)b * 64 + xx) * 64 + yy) * 64 + z) * 32 + part * 8) = o;
}

__global__ void zero_fill(float4* p) {
    p[threadIdx.x] = make_float4(0.f, 0.f, 0.f, 0.f);
}

// ---------------------------------------------------------------------------
// Kernel 3: implicit-GEMM conv via mfma_f32_32x32x16_bf16.
// R6 = R3 structure + TRUE T4: triple-buffered slab, prefetch distance 2,
// counted s_waitcnt vmcnt(5|4) at END of every step (never 0 in the main
// loop), raw s_barrier (no __syncthreads full drain anywhere in the loop).
// R3's dbuf drained slab(t+1) fully at end of step t (issued at top of t,
// single-step window -> HBM latency tail paid at every barrier). Now
// slab(t+2) is issued at top of t into the buffer read at t-1 and stays
// in flight across the barrier; it must land only by end of t+1 (~2-step
// window, ~10k cyc). m201/m218 verified the compiler does NOT force-drain
// vmcnt before plain ds_reads with raw barriers + manual counted waits.
// Block 512 thr (8 waves), tile 4x*8y*64z, grid 16*8*2 = 256 = 1 block/CU.
// LDS 155648 B: Bs[25][2][64][16B] (51200) + slab tbuf 3 x 34816.
// Per-wave slab issue count: wv<2 -> 5 instrs, wv>=2 -> 4 (vmcnt counts).
// ---------------------------------------------------------------------------
__global__ __launch_bounds__(512, 2) void conv_mfma(
    const unsigned short* __restrict__ xt,   // [b][64][64][64][32] bf16
    const unsigned short* __restrict__ kwb,  // [125][2][64][8]
    const unsigned short* __restrict__ zpage,
    float* __restrict__ out)                 // [b][32][64][64][64]
{
    extern __shared__ unsigned short smem[];
    char* lds = (char*)smem;

    const int tid = threadIdx.x;
    const int lane = tid & 63;
    const int wv = tid >> 6;                 // 0..7
    const int oyp = wv >> 1, zh = wv & 1;    // oy pair 0..3, z half
    const int x0 = blockIdx.x * 4, y0 = blockIdx.y * 8;
    const int b = blockIdx.z;
    const int l31 = lane & 31, hi = lane >> 5;

    // A-read base (buf0, oyi=0), includes the 51200 Bs offset; oyi=1: +4352
    // (ds offset imm); other buffers: + runtime rd in {0,34816,69632}.
    int abase[5][2];
#pragma unroll
    for (int dz = 0; dz < 5; ++dz) {
        const int s = zh * 32 + l31 + dz;
#pragma unroll
        for (int kh = 0; kh < 2; ++kh) {
            const int cph = (kh * 2 + hi) ^ ((s >> 1) & 3);
            abase[dz][kh] =
                51200 + ((((oyp * 2 * 68 + s) << 2) | cph) << 4);
        }
    }
    const int bbase = lane * 16;

    // slab staging precompute: 2176 chunks, c = tid + p*512
    // (p<4 all threads; p==4 only waves 0-1)
    int srow[5]; int soff[5]; bool szok[5];
#pragma unroll
    for (int p = 0; p < 5; ++p) {
        const int c = tid + p * 512;
        const int row = c / 272;
        const int rem = c - row * 272;
        const int slot = rem >> 2;
        const int clog = (rem & 3) ^ ((slot >> 1) & 3);
        const int z = slot - 2;
        srow[p] = row;
        szok[p] = ((unsigned)z < 64u);
        soff[p] = row * 2048 + z * 32 + clog * 8;
    }

    // Bs staging precompute: 3200 chunks, c = tid + k*512
    int bsrc[7];
#pragma unroll
    for (int k = 0; k < 7; ++k) {
        const int c = tid + k * 512;
        const int tp = c >> 7, rem = c & 127;
        const int dxx = tp / 5, dzz = tp - dxx * 5;
        bsrc[k] = (dxx * 25 + dzz) * 128 + rem;
    }

    auto issue_bs = [&](int dy) {
#pragma unroll
        for (int k = 0; k < 7; ++k) {
            const int c0 = wv * 64 + k * 512;   // wave-uniform dest base
            if (c0 < 3200) {
                gld_lds16(kwb + ((size_t)(bsrc[k] + dy * 640)) * 8,
                          lds + c0 * 16);
            }
        }
    };

    auto issue_slab = [&](int dyn, int xln, int dstoff) {
        const int yyb = y0 + dyn - 2;
        const int xx = x0 + xln - 2;
        const bool xok = ((unsigned)xx < 64u);
        const long long xyb =
            (long long)(b * 64 + xx) * 131072 + (long long)yyb * 2048;
        char* dst = lds + 51200 + dstoff;    // dstoff uniform
#pragma unroll
        for (int p = 0; p < 4; ++p) {
            const int yy = yyb + srow[p];
            const bool ok = xok && ((unsigned)yy < 64u) && szok[p];
            const unsigned short* src = ok ? (xt + xyb + soff[p]) : zpage;
            gld_lds16(src, dst + (wv * 64 + p * 512) * 16);
        }
        if (wv < 2) {   // chunks 2048..2175
            const int yy = yyb + srow[4];
            const bool ok = xok && ((unsigned)yy < 64u) && szok[4];
            const unsigned short* src = ok ? (xt + xyb + soff[4]) : zpage;
            gld_lds16(src, dst + (wv * 64 + 2048) * 16);
        }
    };

    // counted wait: retire everything older than my newest slab issue
    auto wait_keep_slab = [&]() {
        if (wv < 2) asm volatile("s_waitcnt vmcnt(5)" ::: "memory");
        else        asm volatile("s_waitcnt vmcnt(4)" ::: "memory");
    };

    f32x16 acc[2][4];
#pragma unroll
    for (int oyi = 0; oyi < 2; ++oyi)
#pragma unroll
        for (int ox = 0; ox < 4; ++ox)
#pragma unroll
            for (int e = 0; e < 16; ++e) acc[oyi][ox][e] = 0.0f;

    // prologue: Bs(0), slab(0)->buf0, slab(1)->buf1; retire Bs+slab(0),
    // keep slab(1) in flight.
    issue_bs(0);
    __builtin_amdgcn_sched_barrier(0);
    issue_slab(0, 0, 0);
    __builtin_amdgcn_sched_barrier(0);
    issue_slab(0, 1, 34816);
    __builtin_amdgcn_sched_barrier(0);
    wait_keep_slab();
    __builtin_amdgcn_s_barrier();

    int rd = 0;            // buffer being computed this step
    int prev = 69632;      // buffer read last step = stage target for t+2

    for (int dy = 0; dy < 5; ++dy) {
#pragma unroll
        for (int xl = 0; xl < 8; ++xl) {
            const bool bdry = (xl == 0) && (dy > 0);
            if (bdry) {
                // Bs(dy): all readers of Bs(dy-1) passed last barrier
                issue_bs(dy);
                __builtin_amdgcn_sched_barrier(0);
            }
            // stage slab(t+2) into the buffer read at t-1
            if (!(dy == 4 && xl >= 6)) {
                const int ndy = (xl >= 6) ? dy + 1 : dy;
                const int nxl = (xl >= 6) ? xl - 6 : xl + 2;
                issue_slab(ndy, nxl, prev);
                __builtin_amdgcn_sched_barrier(0);
            }
            if (bdry) {
                // retire slab(t+1)+Bs(dy), keep slab(t+2) in flight
                wait_keep_slab();
                __builtin_amdgcn_s_barrier();
            }

            // compute from buf at rd (runtime uniform offset)
#pragma unroll
            for (int dz = 0; dz < 5; ++dz) {
#pragma unroll
                for (int kh = 0; kh < 2; ++kh) {
                    const char* ap = lds + abase[dz][kh] + rd;
                    const short8 a0 =
                        *reinterpret_cast<const short8*>(ap);
                    const short8 a1 =
                        *reinterpret_cast<const short8*>(ap + 4352);
#pragma unroll
                    for (int ox = 0; ox < 4; ++ox) {
                        const int dxv = xl - ox;
                        if (dxv < 0 || dxv > 4) continue;
                        const short8 bf = *reinterpret_cast<const short8*>(
                            lds + bbase + (((dxv * 5 + dz) * 2 + kh) << 10));
                        acc[0][ox] = __builtin_amdgcn_mfma_f32_32x32x16_bf16(
                            a0, bf, acc[0][ox], 0, 0, 0);
                        acc[1][ox] = __builtin_amdgcn_mfma_f32_32x32x16_bf16(
                            a1, bf, acc[1][ox], 0, 0, 0);
                    }
                }
            }

            // end of step: retire slab(t+1), keep slab(t+2) in flight
            if (dy == 4 && xl >= 6) {
                asm volatile("s_waitcnt vmcnt(0)" ::: "memory");
            } else {
                wait_keep_slab();
            }
            if (!(dy == 4 && xl == 7))
                __builtin_amdgcn_s_barrier();

            // rotate buffers
            const int tmp = rd;
            rd = (rd == 69632) ? 0 : rd + 34816;
            prev = tmp;
        }
    }

    // epilogue: D lane l: co = l&31, z = zh*32 + rq*8 + (l>>5)*4 + (r&3)
#pragma unroll
    for (int oyi = 0; oyi < 2; ++oyi) {
        const int yy = y0 + oyp * 2 + oyi;
#pragma unroll
        for (int ox = 0; ox < 4; ++ox) {
            float* base = out +
                ((((size_t)b * 32 + l31) * 64 + (x0 + ox)) * 64 + yy) * 64 +
                zh * 32 + hi * 4;
#pragma unroll
            for (int rq = 0; rq < 4; ++rq) {
                f32x4 v = { acc[oyi][ox][rq * 4 + 0], acc[oyi][ox][rq * 4 + 1],
                            acc[oyi][ox][rq * 4 + 2], acc[oyi][ox][rq * 4 + 3] };
                *reinterpret_cast<f32x4*>(base + rq * 8) = v;
            }
        }
    }
}

// ---------------------------------------------------------------------------
extern "C" void kernel_launch(void* const* d_in, const int* in_sizes, int n_in,
                              void* d_out, int out_size, void* d_ws, size_t ws_size,
                              hipStream_t stream) {
    const float* x      = (const float*)d_in[0];
    const float* weight = (const float*)d_in[1];
    const float* w_sc0  = (const float*)d_in[2];
    const float* w_sc1  = (const float*)d_in[3];
    float* out = (float*)d_out;

    char* ws = (char*)d_ws;
    unsigned short* xt  = (unsigned short*)ws;                 // 33,554,432 B
    unsigned short* kwb = (unsigned short*)(ws + 33554432);    //    256,000 B
    unsigned short* zpg = (unsigned short*)(ws + 33810432);    //      4,096 B

    (void)hipFuncSetAttribute((const void*)conv_mfma,
                              hipFuncAttributeMaxDynamicSharedMemorySize,
                              155648);

    hipLaunchKernelGGL(build_pack, dim3(NTAP), dim3(128), 0, stream,
                       weight, w_sc0, w_sc1, kwb);
    hipLaunchKernelGGL(xpose, dim3(64, 64, 2), dim3(256), 0, stream, x, xt);
    hipLaunchKernelGGL(zero_fill, dim3(1), dim3(256), 0, stream, (float4*)zpg);
    hipLaunchKernelGGL(conv_mfma, dim3(16, 8, 2), dim3(512), 155648, stream,
                       xt, kwb, zpg, out);
}